// Round 10
// baseline (51.983 us; speedup 1.0000x reference)
//
#include <hip/hip_runtime.h>

// SoftPixelCNN: out[v, o*64+f] = (1/K) * sum_k exp(-A*d[o,v,k]) * feats[nidx[v,k], f]
// d[o,v,k] = ||(c_v + off_o) - c_n||^2, A = 10*length_scale.
// Offsets (meshgrid-xy order): [0, -e1, -e0, -e2, -e3, +e3, +e2, +e0, +e1].
// NUMERICS: exponentiate the COMBINED exponent (always <= 0) -> no 0*inf NaN.
// r6: wave-uniform ballot skip (maxarg < threshold): dropped contribution ~e^T*|g|,
//     T=-12 -> ~3e-5 vs threshold 2.3e-3.
// r9: two vertices per wave (lanes 0-31: v0, 32-63: v1), merged 64-bit mask.
// r10: walk the mask 4 bits at a time; issue up to 4 independent feature-row loads
//      BEFORE the FMA blocks -> 4 gathers in flight per wave (was 1). NT nidx load.

#define KNB 32
#define FDIM 64
#define ODIM 9

__global__ __launch_bounds__(256) void spcnn_kernel(
    const float* __restrict__ coords,   // (V,4)
    const float* __restrict__ feats,    // (V,64)
    const int*   __restrict__ nidx,     // (V,32)
    const float* __restrict__ lscale,   // (1,)
    float* __restrict__ out)            // (V,576)
{
    const int lane = threadIdx.x & 63;
    const int v0 = (blockIdx.x * 4 + (threadIdx.x >> 6)) * 2;  // wave owns v0, v0+1
    const int myv = v0 + (lane >> 5);                          // my half's vertex

    const float A = 10.0f * lscale[0];
    // one coalesced 256B read-once load (NT: don't pollute L2)
    const int myidx = __builtin_nontemporal_load(&nidx[v0 * KNB + lane]);

    // ---- phase 1: exponents for (myv, k=lane&31); 64-bit keep ballot ----
    const float4 cn = *(const float4*)(coords + (size_t)(unsigned)myidx * 4);
    const float4 cv = *(const float4*)(coords + (size_t)myv * 4);
    const float d0 = cv.x - cn.x, d1 = cv.y - cn.y, d2 = cv.z - cn.z, d3 = cv.w - cn.w;
    const float base = d0*d0 + d1*d1 + d2*d2 + d3*d3;

    const float ex = -A * base;                 // origin-offset exponent
    const float bm = ex - A;                    // minus A*||off||^2 (=1 for axis offsets)
    const float t0 = 2.f*A*d0, t1 = 2.f*A*d1, t2 = 2.f*A*d2, t3 = 2.f*A*d3;

    const float mt = fmaxf(fmaxf(fabsf(t0), fabsf(t1)), fmaxf(fabsf(t2), fabsf(t3)));
    const float maxarg = fmaxf(ex, bm + mt);    // exact max over the 9 exponents
    const bool alive = (maxarg >= -12.0f);
    unsigned long long m = __ballot(alive);     // low 32: v0, high 32: v1

    float w0=0.f,w1=0.f,w2=0.f,w3=0.f,w4=0.f,w5=0.f,w6=0.f,w7=0.f,w8=0.f;
    if (alive) {
        const float s = 1.0f / (float)KNB;      // fold mean-over-K
        w0 = __expf(ex)      * s;
        w1 = __expf(bm + t1) * s;               // o = -e1
        w2 = __expf(bm + t0) * s;               // o = -e0
        w3 = __expf(bm + t2) * s;               // o = -e2
        w4 = __expf(bm + t3) * s;               // o = -e3
        w5 = __expf(bm - t3) * s;               // o = +e3
        w6 = __expf(bm - t2) * s;               // o = +e2
        w7 = __expf(bm - t0) * s;               // o = +e0
        w8 = __expf(bm - t1) * s;               // o = +e1
    }

    // ---- phase 2: lane = feature f; 4-wide batched walk of the live mask ----
    float a0=0.f,a1=0.f,a2=0.f,a3=0.f,a4=0.f,a5=0.f,a6=0.f,a7=0.f,a8=0.f;  // v0
    float b0=0.f,b1=0.f,b2=0.f,b3=0.f,b4=0.f,b5=0.f,b6=0.f,b7=0.f,b8=0.f;  // v1

    auto PROC = [&](int kk, float gg) {
        const float s0 = __int_as_float(__builtin_amdgcn_readlane(__float_as_int(w0), kk));
        const float s1 = __int_as_float(__builtin_amdgcn_readlane(__float_as_int(w1), kk));
        const float s2 = __int_as_float(__builtin_amdgcn_readlane(__float_as_int(w2), kk));
        const float s3 = __int_as_float(__builtin_amdgcn_readlane(__float_as_int(w3), kk));
        const float s4 = __int_as_float(__builtin_amdgcn_readlane(__float_as_int(w4), kk));
        const float s5 = __int_as_float(__builtin_amdgcn_readlane(__float_as_int(w5), kk));
        const float s6 = __int_as_float(__builtin_amdgcn_readlane(__float_as_int(w6), kk));
        const float s7 = __int_as_float(__builtin_amdgcn_readlane(__float_as_int(w7), kk));
        const float s8 = __int_as_float(__builtin_amdgcn_readlane(__float_as_int(w8), kk));
        if (kk < KNB) {   // wave-uniform: v0's accumulators
            a0 = fmaf(s0, gg, a0); a1 = fmaf(s1, gg, a1); a2 = fmaf(s2, gg, a2);
            a3 = fmaf(s3, gg, a3); a4 = fmaf(s4, gg, a4); a5 = fmaf(s5, gg, a5);
            a6 = fmaf(s6, gg, a6); a7 = fmaf(s7, gg, a7); a8 = fmaf(s8, gg, a8);
        } else {
            b0 = fmaf(s0, gg, b0); b1 = fmaf(s1, gg, b1); b2 = fmaf(s2, gg, b2);
            b3 = fmaf(s3, gg, b3); b4 = fmaf(s4, gg, b4); b5 = fmaf(s5, gg, b5);
            b6 = fmaf(s6, gg, b6); b7 = fmaf(s7, gg, b7); b8 = fmaf(s8, gg, b8);
        }
    };

    while (m) {
        const int k0 = __builtin_ctzll(m); m &= m - 1;
        const bool h1 = (m != 0);
        int k1 = 0; if (h1) { k1 = __builtin_ctzll(m); m &= m - 1; }
        const bool h2 = (m != 0);
        int k2 = 0; if (h2) { k2 = __builtin_ctzll(m); m &= m - 1; }
        const bool h3 = (m != 0);
        int k3 = 0; if (h3) { k3 = __builtin_ctzll(m); m &= m - 1; }

        // issue up to 4 independent row gathers before any FMA consumes them
        const unsigned i0 = (unsigned)__builtin_amdgcn_readlane(myidx, k0);
        const float g0 = feats[(size_t)i0 * FDIM + lane];
        float g1 = 0.f, g2 = 0.f, g3 = 0.f;
        if (h1) g1 = feats[(size_t)(unsigned)__builtin_amdgcn_readlane(myidx, k1) * FDIM + lane];
        if (h2) g2 = feats[(size_t)(unsigned)__builtin_amdgcn_readlane(myidx, k2) * FDIM + lane];
        if (h3) g3 = feats[(size_t)(unsigned)__builtin_amdgcn_readlane(myidx, k3) * FDIM + lane];

        PROC(k0, g0);
        if (h1) PROC(k1, g1);
        if (h2) PROC(k2, g2);
        if (h3) PROC(k3, g3);
    }

    // ---- nontemporal stores: write-once stream ----
    float* opa = out + (size_t)v0 * (ODIM * FDIM) + lane;
    __builtin_nontemporal_store(a0, opa + 0*FDIM); __builtin_nontemporal_store(a1, opa + 1*FDIM);
    __builtin_nontemporal_store(a2, opa + 2*FDIM); __builtin_nontemporal_store(a3, opa + 3*FDIM);
    __builtin_nontemporal_store(a4, opa + 4*FDIM); __builtin_nontemporal_store(a5, opa + 5*FDIM);
    __builtin_nontemporal_store(a6, opa + 6*FDIM); __builtin_nontemporal_store(a7, opa + 7*FDIM);
    __builtin_nontemporal_store(a8, opa + 8*FDIM);
    float* opb = out + (size_t)(v0 + 1) * (ODIM * FDIM) + lane;
    __builtin_nontemporal_store(b0, opb + 0*FDIM); __builtin_nontemporal_store(b1, opb + 1*FDIM);
    __builtin_nontemporal_store(b2, opb + 2*FDIM); __builtin_nontemporal_store(b3, opb + 3*FDIM);
    __builtin_nontemporal_store(b4, opb + 4*FDIM); __builtin_nontemporal_store(b5, opb + 5*FDIM);
    __builtin_nontemporal_store(b6, opb + 6*FDIM); __builtin_nontemporal_store(b7, opb + 7*FDIM);
    __builtin_nontemporal_store(b8, opb + 8*FDIM);
}

extern "C" void kernel_launch(void* const* d_in, const int* in_sizes, int n_in,
                              void* d_out, int out_size, void* d_ws, size_t ws_size,
                              hipStream_t stream) {
    const float* coords = (const float*)d_in[0];   // (V,4) f32
    const float* feats  = (const float*)d_in[1];   // (V,64) f32
    // d_in[2] = distsq — unused on the inference path
    const int*   nbidx  = (const int*)d_in[3];     // (V,32) i32
    const float* lscale = (const float*)d_in[4];   // (1,) f32

    const int V = in_sizes[0] / 4;                 // 50000
    // 2 vertices per wave, 4 waves per block -> 8 vertices per block
    spcnn_kernel<<<V / 8, 256, 0, stream>>>(coords, feats, nbidx, lscale, (float*)d_out);
}